// Round 7
// baseline (204.080 us; speedup 1.0000x reference)
//
#include <hip/hip_runtime.h>
#include <math.h>

// Problem constants (B=1, T=1024, E=512, H=8, D=64, M=8, R=1, P=32, CHUNK=128)
// Feature dim F = P*M = 256, flattened f = p*8 + m (consistent everywhere).

// ---------- GEMM: C[M,N] = A[M,K] @ W[N,K]^T + bias[N]  (64x64 tile, fp32) ----------
__global__ __launch_bounds__(256) void gemm_bias_kernel(
    const float* __restrict__ A, const float* __restrict__ W,
    const float* __restrict__ bias, float* __restrict__ C,
    int M, int N, int K)
{
    __shared__ float a_t[16][68];   // [k][row], padded to 68 (272B, 16B-aligned rows)
    __shared__ float w_t[16][68];
    const int tid = threadIdx.x;
    const int n0 = blockIdx.x * 64;
    const int m0 = blockIdx.y * 64;
    const int tx = tid & 15, ty = tid >> 4;
    const int lrow = tid >> 2;        // 0..63
    const int lk4  = (tid & 3) * 4;   // 0,4,8,12
    float acc[4][4];
#pragma unroll
    for (int i = 0; i < 4; ++i)
#pragma unroll
        for (int j = 0; j < 4; ++j) acc[i][j] = 0.f;

    for (int k0 = 0; k0 < K; k0 += 16) {
        float4 av = *(const float4*)&A[(m0 + lrow) * K + k0 + lk4];
        float4 wv = *(const float4*)&W[(n0 + lrow) * K + k0 + lk4];
        a_t[lk4 + 0][lrow] = av.x; a_t[lk4 + 1][lrow] = av.y;
        a_t[lk4 + 2][lrow] = av.z; a_t[lk4 + 3][lrow] = av.w;
        w_t[lk4 + 0][lrow] = wv.x; w_t[lk4 + 1][lrow] = wv.y;
        w_t[lk4 + 2][lrow] = wv.z; w_t[lk4 + 3][lrow] = wv.w;
        __syncthreads();
#pragma unroll
        for (int k = 0; k < 16; ++k) {
            float4 af = *(const float4*)&a_t[k][ty * 4];
            float4 wf = *(const float4*)&w_t[k][tx * 4];
            acc[0][0] += af.x * wf.x; acc[0][1] += af.x * wf.y;
            acc[0][2] += af.x * wf.z; acc[0][3] += af.x * wf.w;
            acc[1][0] += af.y * wf.x; acc[1][1] += af.y * wf.y;
            acc[1][2] += af.y * wf.z; acc[1][3] += af.y * wf.w;
            acc[2][0] += af.z * wf.x; acc[2][1] += af.z * wf.y;
            acc[2][2] += af.z * wf.z; acc[2][3] += af.z * wf.w;
            acc[3][0] += af.w * wf.x; acc[3][1] += af.w * wf.y;
            acc[3][2] += af.w * wf.z; acc[3][3] += af.w * wf.w;
        }
        __syncthreads();
    }
    float4 bv = *(const float4*)&bias[n0 + tx * 4];
#pragma unroll
    for (int i = 0; i < 4; ++i) {
        float4 o;
        o.x = acc[i][0] + bv.x; o.y = acc[i][1] + bv.y;
        o.z = acc[i][2] + bv.z; o.w = acc[i][3] + bv.w;
        *(float4*)&C[(m0 + ty * 4 + i) * N + n0 + tx * 4] = o;
    }
}

// ---------- Features: phi_q/phi_k[h][t][256] from qkv ----------
// One wave per (h,t); 4 waves/block.
__global__ __launch_bounds__(256) void features_kernel(
    const float* __restrict__ qkv, const float* __restrict__ omega,
    const float* __restrict__ W_poly, const float* __restrict__ qn,
    const float* __restrict__ qw, float* __restrict__ phi_q,
    float* __restrict__ phi_k)
{
    __shared__ float xn[4][2][64];
    __shared__ float poly[4][2][32];
    __shared__ float prf[4][2][8];
    const int tid = threadIdx.x;
    const int w = tid >> 6;
    const int lane = tid & 63;
    const int item = blockIdx.x * 4 + w;     // 0..8191
    const int h = item >> 10;
    const int t = item & 1023;

    float xq = qkv[t * 1536 + h * 64 + lane];
    float xk = qkv[t * 1536 + 512 + h * 64 + lane];
    float sq = xq * xq, sk = xk * xk;
#pragma unroll
    for (int o = 32; o; o >>= 1) { sq += __shfl_xor(sq, o); sk += __shfl_xor(sk, o); }
    float xnq = xq / fmaxf(sqrtf(sq), 1e-12f);
    float xnk = xk / fmaxf(sqrtf(sk), 1e-12f);
    xn[w][0][lane] = xnq;
    xn[w][1][lane] = xnk;
    __syncthreads();

    // poly: lanes 0..31 -> q (p=lane), lanes 32..63 -> k
    {
        const int which = lane >> 5;
        const int p = lane & 31;
        float pacc = 0.f;
#pragma unroll 8
        for (int d = 0; d < 64; ++d)
            pacc += xn[w][which][d] * W_poly[(h * 64 + d) * 32 + p];
        poly[w][which][p] = pacc;
    }
    // proj + prf: lanes 0..7 -> q (m=lane), lanes 8..15 -> k
    if (lane < 16) {
        const int wh2 = lane >> 3, m = lane & 7;
        float pr = 0.f;
#pragma unroll 8
        for (int d = 0; d < 64; ++d)
            pr += xn[w][wh2][d] * omega[(h * 64 + d) * 8 + m];
        float s0 = qn[0];
        float sqrt2s = sqrtf(2.f * fmaxf(s0, 0.f));
        float sqw = sqrtf(fmaxf(qw[0], 0.f));
        float z = fminf(fmaxf(pr * sqrt2s - s0, -20.f), 20.f);
        prf[w][wh2][m] = expf(z) * 0.3535533905932738f * sqw; // /sqrt(M) * sqrt(weight)
    }
    __syncthreads();

    // write phi: each lane writes 4 consecutive f = lane*4+j; p = lane>>1, m = (lane&1)*4+j
    const int pp = lane >> 1;
    const int mb = (lane & 1) * 4;
    float qp = poly[w][0][pp], kp = poly[w][1][pp];
    float4 oq, ok;
    oq.x = qp * prf[w][0][mb + 0]; oq.y = qp * prf[w][0][mb + 1];
    oq.z = qp * prf[w][0][mb + 2]; oq.w = qp * prf[w][0][mb + 3];
    ok.x = kp * prf[w][1][mb + 0]; ok.y = kp * prf[w][1][mb + 1];
    ok.z = kp * prf[w][1][mb + 2]; ok.w = kp * prf[w][1][mb + 3];
    *(float4*)&phi_q[((h << 10) + t) * 256 + lane * 4] = oq;
    *(float4*)&phi_k[((h << 10) + t) * 256 + lane * 4] = ok;
}

// ---------- Chunk sums: S_chunk[h][c][f][d] = sum_s phi_k[s][f]*v[s][d]; z_chunk[h][c][f] ----------
// grid = (h,c,fg) = 8*8*4 = 256 blocks; block computes a 64(f) x 64(d) tile
// with a 4x4 micro-tile per thread (outer-product form, VALU-bound).
__global__ __launch_bounds__(256) void chunksum_kernel(
    const float* __restrict__ phi_k, const float* __restrict__ qkv,
    float* __restrict__ S_chunk, float* __restrict__ z_chunk)
{
    __shared__ float pk[128][64];  // [s][f_local]  32KB
    __shared__ float vv[128][64];  // [s][d]        32KB
    const int tid = threadIdx.x;
    const int h  = blockIdx.x >> 5;
    const int c  = (blockIdx.x >> 2) & 7;
    const int fg = blockIdx.x & 3;
    const int f0 = fg * 64;

    // stage pk slice: 128 x 64 floats = 2048 float4
#pragma unroll
    for (int i = 0; i < 8; ++i) {
        int e4 = i * 256 + tid;
        int s = e4 >> 4;
        int f4 = (e4 & 15) * 4;
        *(float4*)&pk[s][f4] =
            *(const float4*)&phi_k[((h << 10) + c * 128 + s) * 256 + f0 + f4];
    }
    // stage v: 128 x 64 floats
#pragma unroll
    for (int i = 0; i < 8; ++i) {
        int e4 = i * 256 + tid;
        int s = e4 >> 4;
        int d4 = (e4 & 15) * 4;
        *(float4*)&vv[s][d4] =
            *(const float4*)&qkv[(c * 128 + s) * 1536 + 1024 + h * 64 + d4];
    }
    __syncthreads();

    const int tx = tid & 15;      // d-block: d = tx*4 ..
    const int ty = tid >> 4;      // f-block: f_local = ty*4 ..
    float acc[4][4];
#pragma unroll
    for (int i = 0; i < 4; ++i)
#pragma unroll
        for (int j = 0; j < 4; ++j) acc[i][j] = 0.f;

    for (int s = 0; s < 128; ++s) {
        float4 pv = *(const float4*)&pk[s][ty * 4];
        float4 v4 = *(const float4*)&vv[s][tx * 4];
        acc[0][0] += pv.x * v4.x; acc[0][1] += pv.x * v4.y;
        acc[0][2] += pv.x * v4.z; acc[0][3] += pv.x * v4.w;
        acc[1][0] += pv.y * v4.x; acc[1][1] += pv.y * v4.y;
        acc[1][2] += pv.y * v4.z; acc[1][3] += pv.y * v4.w;
        acc[2][0] += pv.z * v4.x; acc[2][1] += pv.z * v4.y;
        acc[2][2] += pv.z * v4.z; acc[2][3] += pv.z * v4.w;
        acc[3][0] += pv.w * v4.x; acc[3][1] += pv.w * v4.y;
        acc[3][2] += pv.w * v4.z; acc[3][3] += pv.w * v4.w;
    }

    // z for this block's 64 f values (wave 0 only; pk stable, no sync needed)
    if (tid < 64) {
        float zacc = 0.f;
        for (int s = 0; s < 128; ++s) zacc += pk[s][tid];
        z_chunk[(h * 8 + c) * 256 + f0 + tid] = zacc;
    }

#pragma unroll
    for (int i = 0; i < 4; ++i) {
        float4 o = make_float4(acc[i][0], acc[i][1], acc[i][2], acc[i][3]);
        *(float4*)&S_chunk[((h * 8 + c) * 256 + f0 + ty * 4 + i) * 64 + tx * 4] = o;
    }
}

// ---------- Exclusive prefix over chunks ----------
__global__ __launch_bounds__(256) void scan_kernel(
    const float* __restrict__ S_chunk, const float* __restrict__ z_chunk,
    float* __restrict__ S_prev, float* __restrict__ z_prev)
{
    int gid = blockIdx.x * 256 + threadIdx.x;
    if (gid < 8 * 256 * 64) {
        int h = gid >> 14;
        int r = gid & 16383;         // f*64+d
        float acc = 0.f;
#pragma unroll
        for (int c = 0; c < 8; ++c) {
            int idx = ((h * 8 + c) << 14) + r;
            S_prev[idx] = acc;
            acc += S_chunk[idx];
        }
    }
    if (gid < 2048) {
        int h = gid >> 8, f = gid & 255;
        float acc = 0.f;
#pragma unroll
        for (int c = 0; c < 8; ++c) {
            int idx = (h * 8 + c) * 256 + f;
            z_prev[idx] = acc;
            acc += z_chunk[idx];
        }
    }
}

// ---------- Attention output per (h, c, quarter): 32 rows x 64 d ----------
// 512 threads, wave-specialized, software-pipelined:
//   per ft-iter: [barrier] regs->LDS; issue prefetch(ft+1) to regs; [barrier]; compute(ft)
// so global-load latency of the next slice hides under the current compute.
// v_lds dropped (tail reads V from global, L1/L2-hot) -> LDS ~55KB -> 2 blocks/CU.
__global__ __launch_bounds__(512, 4) void attn_kernel(
    const float* __restrict__ phi_q, const float* __restrict__ phi_k,
    const float* __restrict__ qkv, const float* __restrict__ S_prev,
    const float* __restrict__ z_prev, float* __restrict__ attn)
{
    __shared__ float A_lds[32 * 132];      // 16.5 KB [t_local][s]
    __shared__ float phq_t[32][36];        //  4.5 KB [f][t]
    __shared__ float phk_t[32][132];       // 16.5 KB [f][s]
    __shared__ float Sst[32][64];          //  8.0 KB [f][d]
    __shared__ float ctx_lds[32][64];      //  8.0 KB [t_local][d]
    __shared__ float z_lds[256];
    __shared__ float den_lds[32];
    const int tid = threadIdx.x;
    const int h = blockIdx.x >> 3, c = blockIdx.x & 7;
    const int tb = blockIdx.y * 32;        // row base within chunk
    const int SMAX = tb + 32;              // columns needed: s < SMAX

    const int hc128 = (h << 10) + c * 128;   // row base in phi arrays
    const int hcS   = (h * 8 + c) * 256;     // row base in S_prev/z_prev

    if (tid < 256) z_lds[tid] = z_prev[hcS + tid];

    // staging identity (all 512 threads)
    const int fidx = tid & 31;       // f within 32-slice (phq/phk)
    const int srow = tid >> 5;       // 0..15
    const int frow = tid >> 6;       // 0..7 (Sst)
    const int sdd  = tid & 63;       // d (Sst)

    // A-wave identity (tid < 256): rows 4*tt.., cols 4*ss..
    const int tt = tid >> 5, ss = tid & 31;
    const bool ssActive = (ss * 4) < SMAX;
    // inter-wave identity (tid >= 256): d, row group tg*8..
    const int u = tid & 255;
    const int d = u & 63, tg = u >> 6;

    float acc[4][4];
    float acc2[8];
    float den_acc = 0.f;
#pragma unroll
    for (int i = 0; i < 4; ++i)
#pragma unroll
        for (int j = 0; j < 4; ++j) acc[i][j] = 0.f;
#pragma unroll
    for (int i = 0; i < 8; ++i) acc2[i] = 0.f;

    // ---- prefetch registers ----
    float r_q0, r_q1, r_k[8], r_s[4];
#define LOAD_SLICE(F0)                                                        \
    do {                                                                      \
        r_q0 = phi_q[((hc128 + tb + srow) << 8) + (F0) + fidx];               \
        r_q1 = phi_q[((hc128 + tb + srow + 16) << 8) + (F0) + fidx];          \
        _Pragma("unroll")                                                     \
        for (int k = 0; k < 8; ++k) {                                         \
            int s_ = srow + 16 * k;                                           \
            r_k[k] = (s_ < SMAX) ? phi_k[((hc128 + s_) << 8) + (F0) + fidx]   \
                                 : 0.f;                                       \
        }                                                                     \
        _Pragma("unroll")                                                     \
        for (int k = 0; k < 4; ++k)                                           \
            r_s[k] = S_prev[((hcS + (F0) + frow + 8 * k) << 6) + sdd];        \
    } while (0)

    LOAD_SLICE(0);

    for (int ft = 0; ft < 8; ++ft) {
        const int f0 = ft * 32;
        __syncthreads();                   // prev compute done reading LDS
        // regs -> LDS
        phq_t[fidx][srow]      = r_q0;
        phq_t[fidx][srow + 16] = r_q1;
#pragma unroll
        for (int k = 0; k < 8; ++k) phk_t[fidx][srow + 16 * k] = r_k[k];
#pragma unroll
        for (int k = 0; k < 4; ++k) Sst[frow + 8 * k][sdd] = r_s[k];
        // issue next slice's loads (latency hidden under compute below)
        if (ft < 7) LOAD_SLICE(f0 + 32);
        __syncthreads();

        if (tid < 256) {
            if (ssActive) {
#pragma unroll 4
                for (int f = 0; f < 32; ++f) {
                    float4 av = *(const float4*)&phq_t[f][tt * 4];
                    float4 bv = *(const float4*)&phk_t[f][ss * 4];
                    acc[0][0] += av.x * bv.x; acc[0][1] += av.x * bv.y;
                    acc[0][2] += av.x * bv.z; acc[0][3] += av.x * bv.w;
                    acc[1][0] += av.y * bv.x; acc[1][1] += av.y * bv.y;
                    acc[1][2] += av.y * bv.z; acc[1][3] += av.y * bv.w;
                    acc[2][0] += av.z * bv.x; acc[2][1] += av.z * bv.y;
                    acc[2][2] += av.z * bv.z; acc[2][3] += av.z * bv.w;
                    acc[3][0] += av.w * bv.x; acc[3][1] += av.w * bv.y;
                    acc[3][2] += av.w * bv.z; acc[3][3] += av.w * bv.w;
                }
            }
        } else {
#pragma unroll 4
            for (int f = 0; f < 32; ++f) {
                float sval = Sst[f][d];
                float4 a0 = *(const float4*)&phq_t[f][tg * 8];
                float4 a1 = *(const float4*)&phq_t[f][tg * 8 + 4];
                acc2[0] += a0.x * sval; acc2[1] += a0.y * sval;
                acc2[2] += a0.z * sval; acc2[3] += a0.w * sval;
                acc2[4] += a1.x * sval; acc2[5] += a1.y * sval;
                acc2[6] += a1.z * sval; acc2[7] += a1.w * sval;
            }
            if (u < 32) {
#pragma unroll
                for (int f = 0; f < 32; ++f)
                    den_acc += phq_t[f][u] * z_lds[f0 + f];
            }
        }
    }
#undef LOAD_SLICE

    // ---- handoff: A -> LDS, ctx -> LDS, den -> LDS ----
    if (tid < 256) {
        if (ssActive) {
#pragma unroll
            for (int i = 0; i < 4; ++i) {
                float4 o = make_float4(acc[i][0], acc[i][1], acc[i][2], acc[i][3]);
                *(float4*)&A_lds[(tt * 4 + i) * 132 + ss * 4] = o;
            }
        }
    } else {
#pragma unroll
        for (int i = 0; i < 8; ++i)
            ctx_lds[tg * 8 + i][d] = acc2[i];
        if (u < 32) den_lds[u] = den_acc;
    }
    __syncthreads();

    // ---- masked A*V tail + divide + store (all 512 threads, V from global) ----
    const int dd = tid & 63;
    const int rg = tid >> 6;               // 0..7, rows rg*4..rg*4+3
    const float* vp = qkv + (size_t)(c * 128) * 1536 + 1024 + h * 64 + dd;
#pragma unroll
    for (int i = 0; i < 4; ++i) {
        int tl = rg * 4 + i;               // local row 0..31
        int tcr = tb + tl;                 // row within chunk
        float ctx = ctx_lds[tl][dd];
        float den = den_lds[tl];
        int s = 0;
        for (; s + 3 <= tcr; s += 4) {
            float a0 = A_lds[tl * 132 + s + 0];
            float a1 = A_lds[tl * 132 + s + 1];
            float a2 = A_lds[tl * 132 + s + 2];
            float a3 = A_lds[tl * 132 + s + 3];
            ctx += a0 * vp[(size_t)(s + 0) * 1536] + a1 * vp[(size_t)(s + 1) * 1536]
                 + a2 * vp[(size_t)(s + 2) * 1536] + a3 * vp[(size_t)(s + 3) * 1536];
            den += a0 + a1 + a2 + a3;
        }
        for (; s <= tcr; ++s) {
            float a = A_lds[tl * 132 + s];
            ctx += a * vp[(size_t)s * 1536];
            den += a;
        }
        attn[(c * 128 + tcr) * 512 + h * 64 + dd] = ctx / fmaxf(den, 1e-6f);
    }
}

extern "C" void kernel_launch(void* const* d_in, const int* in_sizes, int n_in,
                              void* d_out, int out_size, void* d_ws, size_t ws_size,
                              hipStream_t stream)
{
    const float* x      = (const float*)d_in[0];
    const float* W_qkv  = (const float*)d_in[1];
    const float* b_qkv  = (const float*)d_in[2];
    const float* W_out  = (const float*)d_in[3];
    const float* b_out  = (const float*)d_in[4];
    const float* omega  = (const float*)d_in[5];
    const float* W_poly = (const float*)d_in[6];
    const float* qn     = (const float*)d_in[7];
    const float* qw     = (const float*)d_in[8];
    float* out = (float*)d_out;

    float* ws    = (float*)d_ws;
    float* qkv   = ws;                    // 1024*1536
    float* phi_q = qkv + 1572864;         // 8*1024*256
    float* phi_k = phi_q + 2097152;       // 8*1024*256
    float* S_c   = phi_k + 2097152;       // 8*8*256*64
    float* z_c   = S_c + 1048576;         // 8*8*256
    float* S_p   = z_c + 16384;           // 8*8*256*64
    float* z_p   = S_p + 1048576;         // 8*8*256
    float* attn  = z_p + 16384;           // 1024*512

    gemm_bias_kernel<<<dim3(24, 16), 256, 0, stream>>>(x, W_qkv, b_qkv, qkv, 1024, 1536, 512);
    features_kernel<<<2048, 256, 0, stream>>>(qkv, omega, W_poly, qn, qw, phi_q, phi_k);
    chunksum_kernel<<<256, 256, 0, stream>>>(phi_k, qkv, S_c, z_c);
    scan_kernel<<<512, 256, 0, stream>>>(S_c, z_c, S_p, z_p);
    attn_kernel<<<dim3(64, 4), 512, 0, stream>>>(phi_q, phi_k, qkv, S_p, z_p, attn);
    gemm_bias_kernel<<<dim3(8, 16), 256, 0, stream>>>(attn, W_out, b_out, out, 1024, 512, 512);
}

// Round 8
// 188.956 us; speedup vs baseline: 1.0800x; 1.0800x over previous
//
#include <hip/hip_runtime.h>
#include <math.h>

// Problem constants (B=1, T=1024, E=512, H=8, D=64, M=8, R=1, P=32, CHUNK=128)
// Feature dim F = P*M = 256, flattened f = p*8 + m (consistent everywhere).

// ---------- GEMM: C[M,N] = A[M,K] @ W[N,K]^T + bias[N]  (64x64 tile, fp32) ----------
__global__ __launch_bounds__(256) void gemm_bias_kernel(
    const float* __restrict__ A, const float* __restrict__ W,
    const float* __restrict__ bias, float* __restrict__ C,
    int M, int N, int K)
{
    __shared__ float a_t[16][68];   // [k][row], padded to 68 (272B, 16B-aligned rows)
    __shared__ float w_t[16][68];
    const int tid = threadIdx.x;
    const int n0 = blockIdx.x * 64;
    const int m0 = blockIdx.y * 64;
    const int tx = tid & 15, ty = tid >> 4;
    const int lrow = tid >> 2;        // 0..63
    const int lk4  = (tid & 3) * 4;   // 0,4,8,12
    float acc[4][4];
#pragma unroll
    for (int i = 0; i < 4; ++i)
#pragma unroll
        for (int j = 0; j < 4; ++j) acc[i][j] = 0.f;

    for (int k0 = 0; k0 < K; k0 += 16) {
        float4 av = *(const float4*)&A[(m0 + lrow) * K + k0 + lk4];
        float4 wv = *(const float4*)&W[(n0 + lrow) * K + k0 + lk4];
        a_t[lk4 + 0][lrow] = av.x; a_t[lk4 + 1][lrow] = av.y;
        a_t[lk4 + 2][lrow] = av.z; a_t[lk4 + 3][lrow] = av.w;
        w_t[lk4 + 0][lrow] = wv.x; w_t[lk4 + 1][lrow] = wv.y;
        w_t[lk4 + 2][lrow] = wv.z; w_t[lk4 + 3][lrow] = wv.w;
        __syncthreads();
#pragma unroll
        for (int k = 0; k < 16; ++k) {
            float4 af = *(const float4*)&a_t[k][ty * 4];
            float4 wf = *(const float4*)&w_t[k][tx * 4];
            acc[0][0] += af.x * wf.x; acc[0][1] += af.x * wf.y;
            acc[0][2] += af.x * wf.z; acc[0][3] += af.x * wf.w;
            acc[1][0] += af.y * wf.x; acc[1][1] += af.y * wf.y;
            acc[1][2] += af.y * wf.z; acc[1][3] += af.y * wf.w;
            acc[2][0] += af.z * wf.x; acc[2][1] += af.z * wf.y;
            acc[2][2] += af.z * wf.z; acc[2][3] += af.z * wf.w;
            acc[3][0] += af.w * wf.x; acc[3][1] += af.w * wf.y;
            acc[3][2] += af.w * wf.z; acc[3][3] += af.w * wf.w;
        }
        __syncthreads();
    }
    float4 bv = *(const float4*)&bias[n0 + tx * 4];
#pragma unroll
    for (int i = 0; i < 4; ++i) {
        float4 o;
        o.x = acc[i][0] + bv.x; o.y = acc[i][1] + bv.y;
        o.z = acc[i][2] + bv.z; o.w = acc[i][3] + bv.w;
        *(float4*)&C[(m0 + ty * 4 + i) * N + n0 + tx * 4] = o;
    }
}

// ---------- Features: phi_q/phi_k[h][t][256] from qkv ----------
// One wave per (h,t); 4 waves/block.
__global__ __launch_bounds__(256) void features_kernel(
    const float* __restrict__ qkv, const float* __restrict__ omega,
    const float* __restrict__ W_poly, const float* __restrict__ qn,
    const float* __restrict__ qw, float* __restrict__ phi_q,
    float* __restrict__ phi_k)
{
    __shared__ float xn[4][2][64];
    __shared__ float poly[4][2][32];
    __shared__ float prf[4][2][8];
    const int tid = threadIdx.x;
    const int w = tid >> 6;
    const int lane = tid & 63;
    const int item = blockIdx.x * 4 + w;     // 0..8191
    const int h = item >> 10;
    const int t = item & 1023;

    float xq = qkv[t * 1536 + h * 64 + lane];
    float xk = qkv[t * 1536 + 512 + h * 64 + lane];
    float sq = xq * xq, sk = xk * xk;
#pragma unroll
    for (int o = 32; o; o >>= 1) { sq += __shfl_xor(sq, o); sk += __shfl_xor(sk, o); }
    float xnq = xq / fmaxf(sqrtf(sq), 1e-12f);
    float xnk = xk / fmaxf(sqrtf(sk), 1e-12f);
    xn[w][0][lane] = xnq;
    xn[w][1][lane] = xnk;
    __syncthreads();

    // poly: lanes 0..31 -> q (p=lane), lanes 32..63 -> k
    {
        const int which = lane >> 5;
        const int p = lane & 31;
        float pacc = 0.f;
#pragma unroll 8
        for (int d = 0; d < 64; ++d)
            pacc += xn[w][which][d] * W_poly[(h * 64 + d) * 32 + p];
        poly[w][which][p] = pacc;
    }
    // proj + prf: lanes 0..7 -> q (m=lane), lanes 8..15 -> k
    if (lane < 16) {
        const int wh2 = lane >> 3, m = lane & 7;
        float pr = 0.f;
#pragma unroll 8
        for (int d = 0; d < 64; ++d)
            pr += xn[w][wh2][d] * omega[(h * 64 + d) * 8 + m];
        float s0 = qn[0];
        float sqrt2s = sqrtf(2.f * fmaxf(s0, 0.f));
        float sqw = sqrtf(fmaxf(qw[0], 0.f));
        float z = fminf(fmaxf(pr * sqrt2s - s0, -20.f), 20.f);
        prf[w][wh2][m] = expf(z) * 0.3535533905932738f * sqw; // /sqrt(M) * sqrt(weight)
    }
    __syncthreads();

    // write phi: each lane writes 4 consecutive f = lane*4+j; p = lane>>1, m = (lane&1)*4+j
    const int pp = lane >> 1;
    const int mb = (lane & 1) * 4;
    float qp = poly[w][0][pp], kp = poly[w][1][pp];
    float4 oq, ok;
    oq.x = qp * prf[w][0][mb + 0]; oq.y = qp * prf[w][0][mb + 1];
    oq.z = qp * prf[w][0][mb + 2]; oq.w = qp * prf[w][0][mb + 3];
    ok.x = kp * prf[w][1][mb + 0]; ok.y = kp * prf[w][1][mb + 1];
    ok.z = kp * prf[w][1][mb + 2]; ok.w = kp * prf[w][1][mb + 3];
    *(float4*)&phi_q[((h << 10) + t) * 256 + lane * 4] = oq;
    *(float4*)&phi_k[((h << 10) + t) * 256 + lane * 4] = ok;
}

// ---------- Chunk sums: S_chunk[h][c][f][d] = sum_s phi_k[s][f]*v[s][d]; z_chunk[h][c][f] ----------
// grid = (h,c,fg) = 8*8*4 = 256 blocks; block computes a 64(f) x 64(d) tile
// with a 4x4 micro-tile per thread (outer-product form, VALU-bound).
__global__ __launch_bounds__(256) void chunksum_kernel(
    const float* __restrict__ phi_k, const float* __restrict__ qkv,
    float* __restrict__ S_chunk, float* __restrict__ z_chunk)
{
    __shared__ float pk[128][64];  // [s][f_local]  32KB
    __shared__ float vv[128][64];  // [s][d]        32KB
    const int tid = threadIdx.x;
    const int h  = blockIdx.x >> 5;
    const int c  = (blockIdx.x >> 2) & 7;
    const int fg = blockIdx.x & 3;
    const int f0 = fg * 64;

    // stage pk slice: 128 x 64 floats = 2048 float4
#pragma unroll
    for (int i = 0; i < 8; ++i) {
        int e4 = i * 256 + tid;
        int s = e4 >> 4;
        int f4 = (e4 & 15) * 4;
        *(float4*)&pk[s][f4] =
            *(const float4*)&phi_k[((h << 10) + c * 128 + s) * 256 + f0 + f4];
    }
    // stage v: 128 x 64 floats
#pragma unroll
    for (int i = 0; i < 8; ++i) {
        int e4 = i * 256 + tid;
        int s = e4 >> 4;
        int d4 = (e4 & 15) * 4;
        *(float4*)&vv[s][d4] =
            *(const float4*)&qkv[(c * 128 + s) * 1536 + 1024 + h * 64 + d4];
    }
    __syncthreads();

    const int tx = tid & 15;      // d-block: d = tx*4 ..
    const int ty = tid >> 4;      // f-block: f_local = ty*4 ..
    float acc[4][4];
#pragma unroll
    for (int i = 0; i < 4; ++i)
#pragma unroll
        for (int j = 0; j < 4; ++j) acc[i][j] = 0.f;

    for (int s = 0; s < 128; ++s) {
        float4 pv = *(const float4*)&pk[s][ty * 4];
        float4 v4 = *(const float4*)&vv[s][tx * 4];
        acc[0][0] += pv.x * v4.x; acc[0][1] += pv.x * v4.y;
        acc[0][2] += pv.x * v4.z; acc[0][3] += pv.x * v4.w;
        acc[1][0] += pv.y * v4.x; acc[1][1] += pv.y * v4.y;
        acc[1][2] += pv.y * v4.z; acc[1][3] += pv.y * v4.w;
        acc[2][0] += pv.z * v4.x; acc[2][1] += pv.z * v4.y;
        acc[2][2] += pv.z * v4.z; acc[2][3] += pv.z * v4.w;
        acc[3][0] += pv.w * v4.x; acc[3][1] += pv.w * v4.y;
        acc[3][2] += pv.w * v4.z; acc[3][3] += pv.w * v4.w;
    }

    // z for this block's 64 f values (wave 0 only; pk stable, no sync needed)
    if (tid < 64) {
        float zacc = 0.f;
        for (int s = 0; s < 128; ++s) zacc += pk[s][tid];
        z_chunk[(h * 8 + c) * 256 + f0 + tid] = zacc;
    }

#pragma unroll
    for (int i = 0; i < 4; ++i) {
        float4 o = make_float4(acc[i][0], acc[i][1], acc[i][2], acc[i][3]);
        *(float4*)&S_chunk[((h * 8 + c) * 256 + f0 + ty * 4 + i) * 64 + tx * 4] = o;
    }
}

// ---------- Exclusive prefix over chunks ----------
__global__ __launch_bounds__(256) void scan_kernel(
    const float* __restrict__ S_chunk, const float* __restrict__ z_chunk,
    float* __restrict__ S_prev, float* __restrict__ z_prev)
{
    int gid = blockIdx.x * 256 + threadIdx.x;
    if (gid < 8 * 256 * 64) {
        int h = gid >> 14;
        int r = gid & 16383;         // f*64+d
        float acc = 0.f;
#pragma unroll
        for (int c = 0; c < 8; ++c) {
            int idx = ((h * 8 + c) << 14) + r;
            S_prev[idx] = acc;
            acc += S_chunk[idx];
        }
    }
    if (gid < 2048) {
        int h = gid >> 8, f = gid & 255;
        float acc = 0.f;
#pragma unroll
        for (int c = 0; c < 8; ++c) {
            int idx = (h * 8 + c) * 256 + f;
            z_prev[idx] = acc;
            acc += z_chunk[idx];
        }
    }
}

// ---------- Attention output per (h, c, quarter): 32 rows x 64 d ----------
// 512 threads, wave-specialized + register-prefetch pipeline:
//   iter ft: [barrier] regs(ft)->LDS [barrier] issue loads(ft+1)->regs; compute(ft)
// Load latency hides under compute; the waitcnt for the loads lands at the
// NEXT iteration's LDS-write, after the barrier. __launch_bounds__(512,1)
// keeps all 14 prefetch loads in distinct VGPRs (round-7 lesson: a (512,4)
// cap -> VGPR 56 -> serialized loads). v_lds tail kept in LDS (coalesced).
__global__ __launch_bounds__(512, 1) void attn_kernel(
    const float* __restrict__ phi_q, const float* __restrict__ phi_k,
    const float* __restrict__ qkv, const float* __restrict__ S_prev,
    const float* __restrict__ z_prev, float* __restrict__ attn)
{
    __shared__ float v_lds[128 * 64];      // 32.0 KB [s][d]
    __shared__ float A_lds[32 * 132];      // 16.9 KB [t_local][s]
    __shared__ float phq_t[32][36];        //  4.6 KB [f][t]
    __shared__ float phk_t[32][132];       // 16.9 KB [f][s]
    __shared__ float Sst[32][68];          //  8.7 KB [f][d] (+4 pad: staggers write banks)
    __shared__ float ctx_lds[32][64];      //  8.0 KB [t_local][d]
    __shared__ float z_lds[256];
    __shared__ float den_lds[32];
    const int tid = threadIdx.x;
    const int h = blockIdx.x >> 3, c = blockIdx.x & 7;
    const int tb = blockIdx.y * 32;        // row base within chunk
    const int SMAX = tb + 32;              // columns needed: s < SMAX

    const int hc128 = (h << 10) + c * 128;   // row base in phi arrays
    const int hcS   = (h * 8 + c) * 256;     // row base in S_prev/z_prev

    // ---- one-time stage: v rows < SMAX (float4, coalesced) and z_prev ----
    for (int e4 = tid; e4 < SMAX * 16; e4 += 512) {
        int s = e4 >> 4;
        int d4 = (e4 & 15) * 4;
        *(float4*)&v_lds[s * 64 + d4] =
            *(const float4*)&qkv[(c * 128 + s) * 1536 + 1024 + h * 64 + d4];
    }
    if (tid < 256) z_lds[tid] = z_prev[hcS + tid];

    // staging identity (all 512 threads)
    const int fidx = tid & 31;       // f within 32-slice
    const int srow = tid >> 5;       // 0..15
    const int frow = tid >> 6;       // 0..7 (Sst)
    const int sdd  = tid & 63;       // d (Sst)

    // A-wave identity (tid < 256): rows 4*tt.., cols 4*ss..
    const int tt = tid >> 5, ss = tid & 31;
    const bool ssActive = (ss * 4) < SMAX;
    // inter-wave identity (tid >= 256): d, row group tg*8..
    const int u = tid & 255;
    const int d = u & 63, tg = u >> 6;

    float acc[4][4];
    float acc2[8];
    float den_acc = 0.f;
#pragma unroll
    for (int i = 0; i < 4; ++i)
#pragma unroll
        for (int j = 0; j < 4; ++j) acc[i][j] = 0.f;
#pragma unroll
    for (int i = 0; i < 8; ++i) acc2[i] = 0.f;

    // ---- prefetch registers (14 floats; coalesced: fidx consecutive per lane) ----
    float r_q0, r_q1, r_k[8], r_s[4];
#define LOAD_SLICE(F0)                                                        \
    do {                                                                      \
        r_q0 = phi_q[((hc128 + tb + srow) << 8) + (F0) + fidx];               \
        r_q1 = phi_q[((hc128 + tb + srow + 16) << 8) + (F0) + fidx];          \
        _Pragma("unroll")                                                     \
        for (int k = 0; k < 8; ++k) {                                         \
            int s_ = srow + 16 * k;                                           \
            r_k[k] = (s_ < SMAX) ? phi_k[((hc128 + s_) << 8) + (F0) + fidx]   \
                                 : 0.f;                                       \
        }                                                                     \
        _Pragma("unroll")                                                     \
        for (int k = 0; k < 4; ++k)                                           \
            r_s[k] = S_prev[((hcS + (F0) + frow + 8 * k) << 6) + sdd];        \
    } while (0)

    LOAD_SLICE(0);

    for (int ft = 0; ft < 8; ++ft) {
        const int f0 = ft * 32;
        __syncthreads();                   // prev compute done reading LDS
        // regs -> LDS
        phq_t[fidx][srow]      = r_q0;
        phq_t[fidx][srow + 16] = r_q1;
#pragma unroll
        for (int k = 0; k < 8; ++k) phk_t[fidx][srow + 16 * k] = r_k[k];
#pragma unroll
        for (int k = 0; k < 4; ++k) Sst[frow + 8 * k][sdd] = r_s[k];
        __syncthreads();
        // issue next slice's loads; latency hides under compute below
        if (ft < 7) LOAD_SLICE(f0 + 32);

        if (tid < 256) {
            if (ssActive) {
#pragma unroll 4
                for (int f = 0; f < 32; ++f) {
                    float4 av = *(const float4*)&phq_t[f][tt * 4];
                    float4 bv = *(const float4*)&phk_t[f][ss * 4];
                    acc[0][0] += av.x * bv.x; acc[0][1] += av.x * bv.y;
                    acc[0][2] += av.x * bv.z; acc[0][3] += av.x * bv.w;
                    acc[1][0] += av.y * bv.x; acc[1][1] += av.y * bv.y;
                    acc[1][2] += av.y * bv.z; acc[1][3] += av.y * bv.w;
                    acc[2][0] += av.z * bv.x; acc[2][1] += av.z * bv.y;
                    acc[2][2] += av.z * bv.z; acc[2][3] += av.z * bv.w;
                    acc[3][0] += av.w * bv.x; acc[3][1] += av.w * bv.y;
                    acc[3][2] += av.w * bv.z; acc[3][3] += av.w * bv.w;
                }
            }
        } else {
#pragma unroll 4
            for (int f = 0; f < 32; ++f) {
                float sval = Sst[f][d];
                float4 a0 = *(const float4*)&phq_t[f][tg * 8];
                float4 a1 = *(const float4*)&phq_t[f][tg * 8 + 4];
                acc2[0] += a0.x * sval; acc2[1] += a0.y * sval;
                acc2[2] += a0.z * sval; acc2[3] += a0.w * sval;
                acc2[4] += a1.x * sval; acc2[5] += a1.y * sval;
                acc2[6] += a1.z * sval; acc2[7] += a1.w * sval;
            }
            if (u < 32) {
#pragma unroll
                for (int f = 0; f < 32; ++f)
                    den_acc += phq_t[f][u] * z_lds[f0 + f];
            }
        }
    }
#undef LOAD_SLICE

    // ---- handoff: A -> LDS, ctx -> LDS, den -> LDS ----
    if (tid < 256) {
        if (ssActive) {
#pragma unroll
            for (int i = 0; i < 4; ++i) {
                float4 o = make_float4(acc[i][0], acc[i][1], acc[i][2], acc[i][3]);
                *(float4*)&A_lds[(tt * 4 + i) * 132 + ss * 4] = o;
            }
        }
    } else {
#pragma unroll
        for (int i = 0; i < 8; ++i)
            ctx_lds[tg * 8 + i][d] = acc2[i];
        if (u < 32) den_lds[u] = den_acc;
    }
    __syncthreads();

    // ---- masked A*V tail + divide + store (all 512 threads, V in LDS) ----
    const int dd = tid & 63;
    const int rg = tid >> 6;               // 0..7, rows rg*4..rg*4+3
#pragma unroll
    for (int i = 0; i < 4; ++i) {
        int tl = rg * 4 + i;               // local row 0..31
        int tcr = tb + tl;                 // row within chunk
        float ctx = ctx_lds[tl][dd];
        float den = den_lds[tl];
        for (int s = 0; s <= tcr; ++s) {
            float a = A_lds[tl * 132 + s];
            ctx += a * v_lds[s * 64 + dd];
            den += a;
        }
        attn[(c * 128 + tcr) * 512 + h * 64 + dd] = ctx / fmaxf(den, 1e-6f);
    }
}

extern "C" void kernel_launch(void* const* d_in, const int* in_sizes, int n_in,
                              void* d_out, int out_size, void* d_ws, size_t ws_size,
                              hipStream_t stream)
{
    const float* x      = (const float*)d_in[0];
    const float* W_qkv  = (const float*)d_in[1];
    const float* b_qkv  = (const float*)d_in[2];
    const float* W_out  = (const float*)d_in[3];
    const float* b_out  = (const float*)d_in[4];
    const float* omega  = (const float*)d_in[5];
    const float* W_poly = (const float*)d_in[6];
    const float* qn     = (const float*)d_in[7];
    const float* qw     = (const float*)d_in[8];
    float* out = (float*)d_out;

    float* ws    = (float*)d_ws;
    float* qkv   = ws;                    // 1024*1536
    float* phi_q = qkv + 1572864;         // 8*1024*256
    float* phi_k = phi_q + 2097152;       // 8*1024*256
    float* S_c   = phi_k + 2097152;       // 8*8*256*64
    float* z_c   = S_c + 1048576;         // 8*8*256
    float* S_p   = z_c + 16384;           // 8*8*256*64
    float* z_p   = S_p + 1048576;         // 8*8*256
    float* attn  = z_p + 16384;           // 1024*512

    gemm_bias_kernel<<<dim3(24, 16), 256, 0, stream>>>(x, W_qkv, b_qkv, qkv, 1024, 1536, 512);
    features_kernel<<<2048, 256, 0, stream>>>(qkv, omega, W_poly, qn, qw, phi_q, phi_k);
    chunksum_kernel<<<256, 256, 0, stream>>>(phi_k, qkv, S_c, z_c);
    scan_kernel<<<512, 256, 0, stream>>>(S_c, z_c, S_p, z_p);
    attn_kernel<<<dim3(64, 4), 512, 0, stream>>>(phi_q, phi_k, qkv, S_p, z_p, attn);
    gemm_bias_kernel<<<dim3(8, 16), 256, 0, stream>>>(attn, W_out, b_out, out, 1024, 512, 512);
}

// Round 9
// 182.008 us; speedup vs baseline: 1.1213x; 1.0382x over previous
//
#include <hip/hip_runtime.h>
#include <math.h>

// Problem constants (B=1, T=1024, E=512, H=8, D=64, M=8, R=1, P=32, CHUNK=128)
// Feature dim F = P*M = 256, flattened f = p*8 + m (consistent everywhere).

// ---------- GEMM: C[M,N] = A[M,K] @ W[N,K]^T + bias[N]  (64x64 tile, fp32) ----------
// Register-prefetch pipeline (validated on attn, round 8): stage k0 from regs,
// barrier, issue k0+16's global loads, compute k0 — load latency hides under
// the 16-step FMA phase instead of sitting in the serial chain.
__global__ __launch_bounds__(256) void gemm_bias_kernel(
    const float* __restrict__ A, const float* __restrict__ W,
    const float* __restrict__ bias, float* __restrict__ C,
    int M, int N, int K)
{
    __shared__ float a_t[16][68];   // [k][row], padded to 68
    __shared__ float w_t[16][68];
    const int tid = threadIdx.x;
    const int n0 = blockIdx.x * 64;
    const int m0 = blockIdx.y * 64;
    const int tx = tid & 15, ty = tid >> 4;
    const int lrow = tid >> 2;        // 0..63
    const int lk4  = (tid & 3) * 4;   // 0,4,8,12
    float acc[4][4];
#pragma unroll
    for (int i = 0; i < 4; ++i)
#pragma unroll
        for (int j = 0; j < 4; ++j) acc[i][j] = 0.f;

    const float* Ap = &A[(m0 + lrow) * K + lk4];
    const float* Wp = &W[(n0 + lrow) * K + lk4];
    float4 ra = *(const float4*)Ap;
    float4 rw = *(const float4*)Wp;

    for (int k0 = 0; k0 < K; k0 += 16) {
        // regs -> LDS (prev compute finished reading at the loop-end barrier)
        a_t[lk4 + 0][lrow] = ra.x; a_t[lk4 + 1][lrow] = ra.y;
        a_t[lk4 + 2][lrow] = ra.z; a_t[lk4 + 3][lrow] = ra.w;
        w_t[lk4 + 0][lrow] = rw.x; w_t[lk4 + 1][lrow] = rw.y;
        w_t[lk4 + 2][lrow] = rw.z; w_t[lk4 + 3][lrow] = rw.w;
        __syncthreads();
        // issue next K-slice's loads; latency hides under compute below
        if (k0 + 16 < K) {
            ra = *(const float4*)(Ap + k0 + 16);
            rw = *(const float4*)(Wp + k0 + 16);
        }
#pragma unroll
        for (int k = 0; k < 16; ++k) {
            float4 af = *(const float4*)&a_t[k][ty * 4];
            float4 wf = *(const float4*)&w_t[k][tx * 4];
            acc[0][0] += af.x * wf.x; acc[0][1] += af.x * wf.y;
            acc[0][2] += af.x * wf.z; acc[0][3] += af.x * wf.w;
            acc[1][0] += af.y * wf.x; acc[1][1] += af.y * wf.y;
            acc[1][2] += af.y * wf.z; acc[1][3] += af.y * wf.w;
            acc[2][0] += af.z * wf.x; acc[2][1] += af.z * wf.y;
            acc[2][2] += af.z * wf.z; acc[2][3] += af.z * wf.w;
            acc[3][0] += af.w * wf.x; acc[3][1] += af.w * wf.y;
            acc[3][2] += af.w * wf.z; acc[3][3] += af.w * wf.w;
        }
        __syncthreads();
    }
    float4 bv = *(const float4*)&bias[n0 + tx * 4];
#pragma unroll
    for (int i = 0; i < 4; ++i) {
        float4 o;
        o.x = acc[i][0] + bv.x; o.y = acc[i][1] + bv.y;
        o.z = acc[i][2] + bv.z; o.w = acc[i][3] + bv.w;
        *(float4*)&C[(m0 + ty * 4 + i) * N + n0 + tx * 4] = o;
    }
}

// ---------- Features: phi_q/phi_k[h][t][256] from qkv ----------
// One wave per (h,t); 4 waves/block.
__global__ __launch_bounds__(256) void features_kernel(
    const float* __restrict__ qkv, const float* __restrict__ omega,
    const float* __restrict__ W_poly, const float* __restrict__ qn,
    const float* __restrict__ qw, float* __restrict__ phi_q,
    float* __restrict__ phi_k)
{
    __shared__ float xn[4][2][64];
    __shared__ float poly[4][2][32];
    __shared__ float prf[4][2][8];
    const int tid = threadIdx.x;
    const int w = tid >> 6;
    const int lane = tid & 63;
    const int item = blockIdx.x * 4 + w;     // 0..8191
    const int h = item >> 10;
    const int t = item & 1023;

    float xq = qkv[t * 1536 + h * 64 + lane];
    float xk = qkv[t * 1536 + 512 + h * 64 + lane];
    float sq = xq * xq, sk = xk * xk;
#pragma unroll
    for (int o = 32; o; o >>= 1) { sq += __shfl_xor(sq, o); sk += __shfl_xor(sk, o); }
    float xnq = xq / fmaxf(sqrtf(sq), 1e-12f);
    float xnk = xk / fmaxf(sqrtf(sk), 1e-12f);
    xn[w][0][lane] = xnq;
    xn[w][1][lane] = xnk;
    __syncthreads();

    // poly: lanes 0..31 -> q (p=lane), lanes 32..63 -> k
    {
        const int which = lane >> 5;
        const int p = lane & 31;
        float pacc = 0.f;
#pragma unroll 8
        for (int d = 0; d < 64; ++d)
            pacc += xn[w][which][d] * W_poly[(h * 64 + d) * 32 + p];
        poly[w][which][p] = pacc;
    }
    // proj + prf: lanes 0..7 -> q (m=lane), lanes 8..15 -> k
    if (lane < 16) {
        const int wh2 = lane >> 3, m = lane & 7;
        float pr = 0.f;
#pragma unroll 8
        for (int d = 0; d < 64; ++d)
            pr += xn[w][wh2][d] * omega[(h * 64 + d) * 8 + m];
        float s0 = qn[0];
        float sqrt2s = sqrtf(2.f * fmaxf(s0, 0.f));
        float sqw = sqrtf(fmaxf(qw[0], 0.f));
        float z = fminf(fmaxf(pr * sqrt2s - s0, -20.f), 20.f);
        prf[w][wh2][m] = expf(z) * 0.3535533905932738f * sqw; // /sqrt(M) * sqrt(weight)
    }
    __syncthreads();

    // write phi: each lane writes 4 consecutive f = lane*4+j; p = lane>>1, m = (lane&1)*4+j
    const int pp = lane >> 1;
    const int mb = (lane & 1) * 4;
    float qp = poly[w][0][pp], kp = poly[w][1][pp];
    float4 oq, ok;
    oq.x = qp * prf[w][0][mb + 0]; oq.y = qp * prf[w][0][mb + 1];
    oq.z = qp * prf[w][0][mb + 2]; oq.w = qp * prf[w][0][mb + 3];
    ok.x = kp * prf[w][1][mb + 0]; ok.y = kp * prf[w][1][mb + 1];
    ok.z = kp * prf[w][1][mb + 2]; ok.w = kp * prf[w][1][mb + 3];
    *(float4*)&phi_q[((h << 10) + t) * 256 + lane * 4] = oq;
    *(float4*)&phi_k[((h << 10) + t) * 256 + lane * 4] = ok;
}

// ---------- Chunk sums: S_chunk[h][c][f][d] = sum_s phi_k[s][f]*v[s][d]; z_chunk[h][c][f] ----------
// grid = (h,c,fg) = 8*8*4 = 256 blocks; block computes a 64(f) x 64(d) tile
// with a 4x4 micro-tile per thread (outer-product form, VALU-bound).
__global__ __launch_bounds__(256) void chunksum_kernel(
    const float* __restrict__ phi_k, const float* __restrict__ qkv,
    float* __restrict__ S_chunk, float* __restrict__ z_chunk)
{
    __shared__ float pk[128][64];  // [s][f_local]  32KB
    __shared__ float vv[128][64];  // [s][d]        32KB
    const int tid = threadIdx.x;
    const int h  = blockIdx.x >> 5;
    const int c  = (blockIdx.x >> 2) & 7;
    const int fg = blockIdx.x & 3;
    const int f0 = fg * 64;

    // stage pk slice: 128 x 64 floats = 2048 float4
#pragma unroll
    for (int i = 0; i < 8; ++i) {
        int e4 = i * 256 + tid;
        int s = e4 >> 4;
        int f4 = (e4 & 15) * 4;
        *(float4*)&pk[s][f4] =
            *(const float4*)&phi_k[((h << 10) + c * 128 + s) * 256 + f0 + f4];
    }
    // stage v: 128 x 64 floats
#pragma unroll
    for (int i = 0; i < 8; ++i) {
        int e4 = i * 256 + tid;
        int s = e4 >> 4;
        int d4 = (e4 & 15) * 4;
        *(float4*)&vv[s][d4] =
            *(const float4*)&qkv[(c * 128 + s) * 1536 + 1024 + h * 64 + d4];
    }
    __syncthreads();

    const int tx = tid & 15;      // d-block: d = tx*4 ..
    const int ty = tid >> 4;      // f-block: f_local = ty*4 ..
    float acc[4][4];
#pragma unroll
    for (int i = 0; i < 4; ++i)
#pragma unroll
        for (int j = 0; j < 4; ++j) acc[i][j] = 0.f;

    for (int s = 0; s < 128; ++s) {
        float4 pv = *(const float4*)&pk[s][ty * 4];
        float4 v4 = *(const float4*)&vv[s][tx * 4];
        acc[0][0] += pv.x * v4.x; acc[0][1] += pv.x * v4.y;
        acc[0][2] += pv.x * v4.z; acc[0][3] += pv.x * v4.w;
        acc[1][0] += pv.y * v4.x; acc[1][1] += pv.y * v4.y;
        acc[1][2] += pv.y * v4.z; acc[1][3] += pv.y * v4.w;
        acc[2][0] += pv.z * v4.x; acc[2][1] += pv.z * v4.y;
        acc[2][2] += pv.z * v4.z; acc[2][3] += pv.z * v4.w;
        acc[3][0] += pv.w * v4.x; acc[3][1] += pv.w * v4.y;
        acc[3][2] += pv.w * v4.z; acc[3][3] += pv.w * v4.w;
    }

    // z for this block's 64 f values (wave 0 only; pk stable, no sync needed)
    if (tid < 64) {
        float zacc = 0.f;
        for (int s = 0; s < 128; ++s) zacc += pk[s][tid];
        z_chunk[(h * 8 + c) * 256 + f0 + tid] = zacc;
    }

#pragma unroll
    for (int i = 0; i < 4; ++i) {
        float4 o = make_float4(acc[i][0], acc[i][1], acc[i][2], acc[i][3]);
        *(float4*)&S_chunk[((h * 8 + c) * 256 + f0 + ty * 4 + i) * 64 + tx * 4] = o;
    }
}

// ---------- Exclusive prefix over chunks ----------
__global__ __launch_bounds__(256) void scan_kernel(
    const float* __restrict__ S_chunk, const float* __restrict__ z_chunk,
    float* __restrict__ S_prev, float* __restrict__ z_prev)
{
    int gid = blockIdx.x * 256 + threadIdx.x;
    if (gid < 8 * 256 * 64) {
        int h = gid >> 14;
        int r = gid & 16383;         // f*64+d
        float acc = 0.f;
#pragma unroll
        for (int c = 0; c < 8; ++c) {
            int idx = ((h * 8 + c) << 14) + r;
            S_prev[idx] = acc;
            acc += S_chunk[idx];
        }
    }
    if (gid < 2048) {
        int h = gid >> 8, f = gid & 255;
        float acc = 0.f;
#pragma unroll
        for (int c = 0; c < 8; ++c) {
            int idx = (h * 8 + c) * 256 + f;
            z_prev[idx] = acc;
            acc += z_chunk[idx];
        }
    }
}

// ---------- Attention output per (h, c, quarter): 32 rows x 64 d ----------
// 512 threads, wave-specialized + register-prefetch pipeline (round-8 form).
__global__ __launch_bounds__(512, 1) void attn_kernel(
    const float* __restrict__ phi_q, const float* __restrict__ phi_k,
    const float* __restrict__ qkv, const float* __restrict__ S_prev,
    const float* __restrict__ z_prev, float* __restrict__ attn)
{
    __shared__ float v_lds[128 * 64];      // 32.0 KB [s][d]
    __shared__ float A_lds[32 * 132];      // 16.9 KB [t_local][s]
    __shared__ float phq_t[32][36];        //  4.6 KB [f][t]
    __shared__ float phk_t[32][132];       // 16.9 KB [f][s]
    __shared__ float Sst[32][68];          //  8.7 KB [f][d] (+4 pad)
    __shared__ float ctx_lds[32][64];      //  8.0 KB [t_local][d]
    __shared__ float z_lds[256];
    __shared__ float den_lds[32];
    const int tid = threadIdx.x;
    const int h = blockIdx.x >> 3, c = blockIdx.x & 7;
    const int tb = blockIdx.y * 32;        // row base within chunk
    const int SMAX = tb + 32;              // columns needed: s < SMAX

    const int hc128 = (h << 10) + c * 128;   // row base in phi arrays
    const int hcS   = (h * 8 + c) * 256;     // row base in S_prev/z_prev

    // ---- one-time stage: v rows < SMAX (float4, coalesced) and z_prev ----
    for (int e4 = tid; e4 < SMAX * 16; e4 += 512) {
        int s = e4 >> 4;
        int d4 = (e4 & 15) * 4;
        *(float4*)&v_lds[s * 64 + d4] =
            *(const float4*)&qkv[(c * 128 + s) * 1536 + 1024 + h * 64 + d4];
    }
    if (tid < 256) z_lds[tid] = z_prev[hcS + tid];

    // staging identity (all 512 threads)
    const int fidx = tid & 31;       // f within 32-slice
    const int srow = tid >> 5;       // 0..15
    const int frow = tid >> 6;       // 0..7 (Sst)
    const int sdd  = tid & 63;       // d (Sst)

    // A-wave identity (tid < 256): rows 4*tt.., cols 4*ss..
    const int tt = tid >> 5, ss = tid & 31;
    const bool ssActive = (ss * 4) < SMAX;
    // inter-wave identity (tid >= 256): d, row group tg*8..
    const int u = tid & 255;
    const int d = u & 63, tg = u >> 6;

    float acc[4][4];
    float acc2[8];
    float den_acc = 0.f;
#pragma unroll
    for (int i = 0; i < 4; ++i)
#pragma unroll
        for (int j = 0; j < 4; ++j) acc[i][j] = 0.f;
#pragma unroll
    for (int i = 0; i < 8; ++i) acc2[i] = 0.f;

    // ---- prefetch registers (14 floats; coalesced: fidx consecutive per lane) ----
    float r_q0, r_q1, r_k[8], r_s[4];
#define LOAD_SLICE(F0)                                                        \
    do {                                                                      \
        r_q0 = phi_q[((hc128 + tb + srow) << 8) + (F0) + fidx];               \
        r_q1 = phi_q[((hc128 + tb + srow + 16) << 8) + (F0) + fidx];          \
        _Pragma("unroll")                                                     \
        for (int k = 0; k < 8; ++k) {                                         \
            int s_ = srow + 16 * k;                                           \
            r_k[k] = (s_ < SMAX) ? phi_k[((hc128 + s_) << 8) + (F0) + fidx]   \
                                 : 0.f;                                       \
        }                                                                     \
        _Pragma("unroll")                                                     \
        for (int k = 0; k < 4; ++k)                                           \
            r_s[k] = S_prev[((hcS + (F0) + frow + 8 * k) << 6) + sdd];        \
    } while (0)

    LOAD_SLICE(0);

    for (int ft = 0; ft < 8; ++ft) {
        const int f0 = ft * 32;
        __syncthreads();                   // prev compute done reading LDS
        // regs -> LDS
        phq_t[fidx][srow]      = r_q0;
        phq_t[fidx][srow + 16] = r_q1;
#pragma unroll
        for (int k = 0; k < 8; ++k) phk_t[fidx][srow + 16 * k] = r_k[k];
#pragma unroll
        for (int k = 0; k < 4; ++k) Sst[frow + 8 * k][sdd] = r_s[k];
        __syncthreads();
        // issue next slice's loads; latency hides under compute below
        if (ft < 7) LOAD_SLICE(f0 + 32);

        if (tid < 256) {
            if (ssActive) {
#pragma unroll 4
                for (int f = 0; f < 32; ++f) {
                    float4 av = *(const float4*)&phq_t[f][tt * 4];
                    float4 bv = *(const float4*)&phk_t[f][ss * 4];
                    acc[0][0] += av.x * bv.x; acc[0][1] += av.x * bv.y;
                    acc[0][2] += av.x * bv.z; acc[0][3] += av.x * bv.w;
                    acc[1][0] += av.y * bv.x; acc[1][1] += av.y * bv.y;
                    acc[1][2] += av.y * bv.z; acc[1][3] += av.y * bv.w;
                    acc[2][0] += av.z * bv.x; acc[2][1] += av.z * bv.y;
                    acc[2][2] += av.z * bv.z; acc[2][3] += av.z * bv.w;
                    acc[3][0] += av.w * bv.x; acc[3][1] += av.w * bv.y;
                    acc[3][2] += av.w * bv.z; acc[3][3] += av.w * bv.w;
                }
            }
        } else {
#pragma unroll 4
            for (int f = 0; f < 32; ++f) {
                float sval = Sst[f][d];
                float4 a0 = *(const float4*)&phq_t[f][tg * 8];
                float4 a1 = *(const float4*)&phq_t[f][tg * 8 + 4];
                acc2[0] += a0.x * sval; acc2[1] += a0.y * sval;
                acc2[2] += a0.z * sval; acc2[3] += a0.w * sval;
                acc2[4] += a1.x * sval; acc2[5] += a1.y * sval;
                acc2[6] += a1.z * sval; acc2[7] += a1.w * sval;
            }
            if (u < 32) {
#pragma unroll
                for (int f = 0; f < 32; ++f)
                    den_acc += phq_t[f][u] * z_lds[f0 + f];
            }
        }
    }
#undef LOAD_SLICE

    // ---- handoff: A -> LDS, ctx -> LDS, den -> LDS ----
    if (tid < 256) {
        if (ssActive) {
#pragma unroll
            for (int i = 0; i < 4; ++i) {
                float4 o = make_float4(acc[i][0], acc[i][1], acc[i][2], acc[i][3]);
                *(float4*)&A_lds[(tt * 4 + i) * 132 + ss * 4] = o;
            }
        }
    } else {
#pragma unroll
        for (int i = 0; i < 8; ++i)
            ctx_lds[tg * 8 + i][d] = acc2[i];
        if (u < 32) den_lds[u] = den_acc;
    }
    __syncthreads();

    // ---- masked A*V tail + divide + store (all 512 threads, V in LDS) ----
    const int dd = tid & 63;
    const int rg = tid >> 6;               // 0..7, rows rg*4..rg*4+3
#pragma unroll
    for (int i = 0; i < 4; ++i) {
        int tl = rg * 4 + i;               // local row 0..31
        int tcr = tb + tl;                 // row within chunk
        float ctx = ctx_lds[tl][dd];
        float den = den_lds[tl];
        for (int s = 0; s <= tcr; ++s) {
            float a = A_lds[tl * 132 + s];
            ctx += a * v_lds[s * 64 + dd];
            den += a;
        }
        attn[(c * 128 + tcr) * 512 + h * 64 + dd] = ctx / fmaxf(den, 1e-6f);
    }
}

extern "C" void kernel_launch(void* const* d_in, const int* in_sizes, int n_in,
                              void* d_out, int out_size, void* d_ws, size_t ws_size,
                              hipStream_t stream)
{
    const float* x      = (const float*)d_in[0];
    const float* W_qkv  = (const float*)d_in[1];
    const float* b_qkv  = (const float*)d_in[2];
    const float* W_out  = (const float*)d_in[3];
    const float* b_out  = (const float*)d_in[4];
    const float* omega  = (const float*)d_in[5];
    const float* W_poly = (const float*)d_in[6];
    const float* qn     = (const float*)d_in[7];
    const float* qw     = (const float*)d_in[8];
    float* out = (float*)d_out;

    float* ws    = (float*)d_ws;
    float* qkv   = ws;                    // 1024*1536
    float* phi_q = qkv + 1572864;         // 8*1024*256
    float* phi_k = phi_q + 2097152;       // 8*1024*256
    float* S_c   = phi_k + 2097152;       // 8*8*256*64
    float* z_c   = S_c + 1048576;         // 8*8*256
    float* S_p   = z_c + 16384;           // 8*8*256*64
    float* z_p   = S_p + 1048576;         // 8*8*256
    float* attn  = z_p + 16384;           // 1024*512

    gemm_bias_kernel<<<dim3(24, 16), 256, 0, stream>>>(x, W_qkv, b_qkv, qkv, 1024, 1536, 512);
    features_kernel<<<2048, 256, 0, stream>>>(qkv, omega, W_poly, qn, qw, phi_q, phi_k);
    chunksum_kernel<<<256, 256, 0, stream>>>(phi_k, qkv, S_c, z_c);
    scan_kernel<<<512, 256, 0, stream>>>(S_c, z_c, S_p, z_p);
    attn_kernel<<<dim3(64, 4), 512, 0, stream>>>(phi_q, phi_k, qkv, S_p, z_p, attn);
    gemm_bias_kernel<<<dim3(8, 16), 256, 0, stream>>>(attn, W_out, b_out, out, 1024, 512, 512);
}

// Round 11
// 168.950 us; speedup vs baseline: 1.2079x; 1.0773x over previous
//
#include <hip/hip_runtime.h>
#include <math.h>

// Problem constants (B=1, T=1024, E=512, H=8, D=64, M=8, R=1, P=32, CHUNK=128)
// Feature dim F = P*M = 256, flattened f = p*8 + m (consistent everywhere).

// ---------- Split-K partial GEMM: part[s][M][N] = A[M,ks]@W[N,ks]^T ----------
// 64x64 tile, 4x4 micro-tile, double-buffered LDS, ONE barrier per K-slice:
//   iter: issue loads(next) -> compute(cur) -> write regs->buf(nxt) -> barrier
// Split-K raises grid (qkv 384->768, out 128->512 blocks) so latency hides via
// TLP; round-9 lesson: out gemm at 128 blocks left half the CUs idle.
__global__ __launch_bounds__(256) void gemm_part_kernel(
    const float* __restrict__ A, const float* __restrict__ W,
    float* __restrict__ part, int M, int N, int K, int Kc)
{
    __shared__ float a_t[2][16][68];   // [buf][k][row]
    __shared__ float w_t[2][16][68];
    const int tid = threadIdx.x;
    const int n0 = blockIdx.x * 64;
    const int m0 = blockIdx.y * 64;
    const int sk = blockIdx.z;
    const int kb = sk * Kc;
    const int tx = tid & 15, ty = tid >> 4;
    const int lrow = tid >> 2;        // 0..63
    const int lk4  = (tid & 3) * 4;   // 0,4,8,12
    float acc[4][4];
#pragma unroll
    for (int i = 0; i < 4; ++i)
#pragma unroll
        for (int j = 0; j < 4; ++j) acc[i][j] = 0.f;

    const float* Ap = &A[(m0 + lrow) * K + kb + lk4];
    const float* Wp = &W[(n0 + lrow) * K + kb + lk4];
    float4 ra = *(const float4*)Ap;
    float4 rw = *(const float4*)Wp;
    // fill buffer 0
    a_t[0][lk4 + 0][lrow] = ra.x; a_t[0][lk4 + 1][lrow] = ra.y;
    a_t[0][lk4 + 2][lrow] = ra.z; a_t[0][lk4 + 3][lrow] = ra.w;
    w_t[0][lk4 + 0][lrow] = rw.x; w_t[0][lk4 + 1][lrow] = rw.y;
    w_t[0][lk4 + 2][lrow] = rw.z; w_t[0][lk4 + 3][lrow] = rw.w;
    __syncthreads();

    int cur = 0;
    for (int k0 = 16; k0 <= Kc; k0 += 16) {
        const bool more = (k0 < Kc);
        if (more) {                      // issue next slice early
            ra = *(const float4*)(Ap + k0);
            rw = *(const float4*)(Wp + k0);
        }
#pragma unroll
        for (int k = 0; k < 16; ++k) {   // compute current buffer
            float4 af = *(const float4*)&a_t[cur][k][ty * 4];
            float4 wf = *(const float4*)&w_t[cur][k][tx * 4];
            acc[0][0] += af.x * wf.x; acc[0][1] += af.x * wf.y;
            acc[0][2] += af.x * wf.z; acc[0][3] += af.x * wf.w;
            acc[1][0] += af.y * wf.x; acc[1][1] += af.y * wf.y;
            acc[1][2] += af.y * wf.z; acc[1][3] += af.y * wf.w;
            acc[2][0] += af.z * wf.x; acc[2][1] += af.z * wf.y;
            acc[2][2] += af.z * wf.z; acc[2][3] += af.z * wf.w;
            acc[3][0] += af.w * wf.x; acc[3][1] += af.w * wf.y;
            acc[3][2] += af.w * wf.z; acc[3][3] += af.w * wf.w;
        }
        if (more) {
            const int nxt = cur ^ 1;
            a_t[nxt][lk4 + 0][lrow] = ra.x; a_t[nxt][lk4 + 1][lrow] = ra.y;
            a_t[nxt][lk4 + 2][lrow] = ra.z; a_t[nxt][lk4 + 3][lrow] = ra.w;
            w_t[nxt][lk4 + 0][lrow] = rw.x; w_t[nxt][lk4 + 1][lrow] = rw.y;
            w_t[nxt][lk4 + 2][lrow] = rw.z; w_t[nxt][lk4 + 3][lrow] = rw.w;
            __syncthreads();
            cur = nxt;
        }
    }
#pragma unroll
    for (int i = 0; i < 4; ++i) {
        float4 o = make_float4(acc[i][0], acc[i][1], acc[i][2], acc[i][3]);
        *(float4*)&part[((size_t)sk * M + m0 + ty * 4 + i) * N + n0 + tx * 4] = o;
    }
}

// ---------- Reduce split-K partials + bias ----------
__global__ __launch_bounds__(256) void reduce_bias_kernel(
    const float* __restrict__ part, const float* __restrict__ bias,
    float* __restrict__ C, int MN, int N, int S)
{
    const int i4 = (blockIdx.x * 256 + threadIdx.x) * 4;
    if (i4 >= MN) return;
    float4 acc = *(const float4*)&part[i4];
    for (int s = 1; s < S; ++s) {
        float4 p = *(const float4*)&part[(size_t)s * MN + i4];
        acc.x += p.x; acc.y += p.y; acc.z += p.z; acc.w += p.w;
    }
    float4 b = *(const float4*)&bias[i4 % N];   // N % 4 == 0
    acc.x += b.x; acc.y += b.y; acc.z += b.z; acc.w += b.w;
    *(float4*)&C[i4] = acc;
}

// ---------- Features: phi_q/phi_k[h][t][256] from qkv ----------
// One wave per (h,t); 4 waves/block.
__global__ __launch_bounds__(256) void features_kernel(
    const float* __restrict__ qkv, const float* __restrict__ omega,
    const float* __restrict__ W_poly, const float* __restrict__ qn,
    const float* __restrict__ qw, float* __restrict__ phi_q,
    float* __restrict__ phi_k)
{
    __shared__ float xn[4][2][64];
    __shared__ float poly[4][2][32];
    __shared__ float prf[4][2][8];
    const int tid = threadIdx.x;
    const int w = tid >> 6;
    const int lane = tid & 63;
    const int item = blockIdx.x * 4 + w;     // 0..8191
    const int h = item >> 10;
    const int t = item & 1023;

    float xq = qkv[t * 1536 + h * 64 + lane];
    float xk = qkv[t * 1536 + 512 + h * 64 + lane];
    float sq = xq * xq, sk = xk * xk;
#pragma unroll
    for (int o = 32; o; o >>= 1) { sq += __shfl_xor(sq, o); sk += __shfl_xor(sk, o); }
    float xnq = xq / fmaxf(sqrtf(sq), 1e-12f);
    float xnk = xk / fmaxf(sqrtf(sk), 1e-12f);
    xn[w][0][lane] = xnq;
    xn[w][1][lane] = xnk;
    __syncthreads();

    // poly: lanes 0..31 -> q (p=lane), lanes 32..63 -> k
    {
        const int which = lane >> 5;
        const int p = lane & 31;
        float pacc = 0.f;
#pragma unroll 8
        for (int d = 0; d < 64; ++d)
            pacc += xn[w][which][d] * W_poly[(h * 64 + d) * 32 + p];
        poly[w][which][p] = pacc;
    }
    // proj + prf: lanes 0..7 -> q (m=lane), lanes 8..15 -> k
    if (lane < 16) {
        const int wh2 = lane >> 3, m = lane & 7;
        float pr = 0.f;
#pragma unroll 8
        for (int d = 0; d < 64; ++d)
            pr += xn[w][wh2][d] * omega[(h * 64 + d) * 8 + m];
        float s0 = qn[0];
        float sqrt2s = sqrtf(2.f * fmaxf(s0, 0.f));
        float sqw = sqrtf(fmaxf(qw[0], 0.f));
        float z = fminf(fmaxf(pr * sqrt2s - s0, -20.f), 20.f);
        prf[w][wh2][m] = expf(z) * 0.3535533905932738f * sqw; // /sqrt(M) * sqrt(weight)
    }
    __syncthreads();

    // write phi: each lane writes 4 consecutive f = lane*4+j; p = lane>>1, m = (lane&1)*4+j
    const int pp = lane >> 1;
    const int mb = (lane & 1) * 4;
    float qp = poly[w][0][pp], kp = poly[w][1][pp];
    float4 oq, ok;
    oq.x = qp * prf[w][0][mb + 0]; oq.y = qp * prf[w][0][mb + 1];
    oq.z = qp * prf[w][0][mb + 2]; oq.w = qp * prf[w][0][mb + 3];
    ok.x = kp * prf[w][1][mb + 0]; ok.y = kp * prf[w][1][mb + 1];
    ok.z = kp * prf[w][1][mb + 2]; ok.w = kp * prf[w][1][mb + 3];
    *(float4*)&phi_q[((h << 10) + t) * 256 + lane * 4] = oq;
    *(float4*)&phi_k[((h << 10) + t) * 256 + lane * 4] = ok;
}

// ---------- Chunk sums: S_chunk[h][c][f][d] = sum_s phi_k[s][f]*v[s][d]; z_chunk[h][c][f] ----------
__global__ __launch_bounds__(256) void chunksum_kernel(
    const float* __restrict__ phi_k, const float* __restrict__ qkv,
    float* __restrict__ S_chunk, float* __restrict__ z_chunk)
{
    __shared__ float pk[128][64];  // [s][f_local]  32KB
    __shared__ float vv[128][64];  // [s][d]        32KB
    const int tid = threadIdx.x;
    const int h  = blockIdx.x >> 5;
    const int c  = (blockIdx.x >> 2) & 7;
    const int fg = blockIdx.x & 3;
    const int f0 = fg * 64;

#pragma unroll
    for (int i = 0; i < 8; ++i) {
        int e4 = i * 256 + tid;
        int s = e4 >> 4;
        int f4 = (e4 & 15) * 4;
        *(float4*)&pk[s][f4] =
            *(const float4*)&phi_k[((h << 10) + c * 128 + s) * 256 + f0 + f4];
    }
#pragma unroll
    for (int i = 0; i < 8; ++i) {
        int e4 = i * 256 + tid;
        int s = e4 >> 4;
        int d4 = (e4 & 15) * 4;
        *(float4*)&vv[s][d4] =
            *(const float4*)&qkv[(c * 128 + s) * 1536 + 1024 + h * 64 + d4];
    }
    __syncthreads();

    const int tx = tid & 15;      // d-block
    const int ty = tid >> 4;      // f-block
    float acc[4][4];
#pragma unroll
    for (int i = 0; i < 4; ++i)
#pragma unroll
        for (int j = 0; j < 4; ++j) acc[i][j] = 0.f;

    for (int s = 0; s < 128; ++s) {
        float4 pv = *(const float4*)&pk[s][ty * 4];
        float4 v4 = *(const float4*)&vv[s][tx * 4];
        acc[0][0] += pv.x * v4.x; acc[0][1] += pv.x * v4.y;
        acc[0][2] += pv.x * v4.z; acc[0][3] += pv.x * v4.w;
        acc[1][0] += pv.y * v4.x; acc[1][1] += pv.y * v4.y;
        acc[1][2] += pv.y * v4.z; acc[1][3] += pv.y * v4.w;
        acc[2][0] += pv.z * v4.x; acc[2][1] += pv.z * v4.y;
        acc[2][2] += pv.z * v4.z; acc[2][3] += pv.z * v4.w;
        acc[3][0] += pv.w * v4.x; acc[3][1] += pv.w * v4.y;
        acc[3][2] += pv.w * v4.z; acc[3][3] += pv.w * v4.w;
    }

    if (tid < 64) {
        float zacc = 0.f;
        for (int s = 0; s < 128; ++s) zacc += pk[s][tid];
        z_chunk[(h * 8 + c) * 256 + f0 + tid] = zacc;
    }

#pragma unroll
    for (int i = 0; i < 4; ++i) {
        float4 o = make_float4(acc[i][0], acc[i][1], acc[i][2], acc[i][3]);
        *(float4*)&S_chunk[((h * 8 + c) * 256 + f0 + ty * 4 + i) * 64 + tx * 4] = o;
    }
}

// ---------- Exclusive prefix over chunks ----------
__global__ __launch_bounds__(256) void scan_kernel(
    const float* __restrict__ S_chunk, const float* __restrict__ z_chunk,
    float* __restrict__ S_prev, float* __restrict__ z_prev)
{
    int gid = blockIdx.x * 256 + threadIdx.x;
    if (gid < 8 * 256 * 64) {
        int h = gid >> 14;
        int r = gid & 16383;
        float acc = 0.f;
#pragma unroll
        for (int c = 0; c < 8; ++c) {
            int idx = ((h * 8 + c) << 14) + r;
            S_prev[idx] = acc;
            acc += S_chunk[idx];
        }
    }
    if (gid < 2048) {
        int h = gid >> 8, f = gid & 255;
        float acc = 0.f;
#pragma unroll
        for (int c = 0; c < 8; ++c) {
            int idx = (h * 8 + c) * 256 + f;
            z_prev[idx] = acc;
            acc += z_chunk[idx];
        }
    }
}

// ---------- Attention output per (h, c, quarter): 32 rows x 64 d ----------
// 512 threads, wave-specialized + register-prefetch pipeline (round-8 form).
__global__ __launch_bounds__(512, 1) void attn_kernel(
    const float* __restrict__ phi_q, const float* __restrict__ phi_k,
    const float* __restrict__ qkv, const float* __restrict__ S_prev,
    const float* __restrict__ z_prev, float* __restrict__ attn)
{
    __shared__ float v_lds[128 * 64];      // 32.0 KB [s][d]
    __shared__ float A_lds[32 * 132];      // 16.9 KB [t_local][s]
    __shared__ float phq_t[32][36];        //  4.6 KB [f][t]
    __shared__ float phk_t[32][132];       // 16.9 KB [f][s]
    __shared__ float Sst[32][68];          //  8.7 KB [f][d] (+4 pad)
    __shared__ float ctx_lds[32][64];      //  8.0 KB [t_local][d]
    __shared__ float z_lds[256];
    __shared__ float den_lds[32];
    const int tid = threadIdx.x;
    const int h = blockIdx.x >> 3, c = blockIdx.x & 7;
    const int tb = blockIdx.y * 32;
    const int SMAX = tb + 32;

    const int hc128 = (h << 10) + c * 128;
    const int hcS   = (h * 8 + c) * 256;

    for (int e4 = tid; e4 < SMAX * 16; e4 += 512) {
        int s = e4 >> 4;
        int d4 = (e4 & 15) * 4;
        *(float4*)&v_lds[s * 64 + d4] =
            *(const float4*)&qkv[(c * 128 + s) * 1536 + 1024 + h * 64 + d4];
    }
    if (tid < 256) z_lds[tid] = z_prev[hcS + tid];

    const int fidx = tid & 31;
    const int srow = tid >> 5;
    const int frow = tid >> 6;
    const int sdd  = tid & 63;

    const int tt = tid >> 5, ss = tid & 31;
    const bool ssActive = (ss * 4) < SMAX;
    const int u = tid & 255;
    const int d = u & 63, tg = u >> 6;

    float acc[4][4];
    float acc2[8];
    float den_acc = 0.f;
#pragma unroll
    for (int i = 0; i < 4; ++i)
#pragma unroll
        for (int j = 0; j < 4; ++j) acc[i][j] = 0.f;
#pragma unroll
    for (int i = 0; i < 8; ++i) acc2[i] = 0.f;

    float r_q0, r_q1, r_k[8], r_s[4];
#define LOAD_SLICE(F0)                                                        \
    do {                                                                      \
        r_q0 = phi_q[((hc128 + tb + srow) << 8) + (F0) + fidx];               \
        r_q1 = phi_q[((hc128 + tb + srow + 16) << 8) + (F0) + fidx];          \
        _Pragma("unroll")                                                     \
        for (int k = 0; k < 8; ++k) {                                         \
            int s_ = srow + 16 * k;                                           \
            r_k[k] = (s_ < SMAX) ? phi_k[((hc128 + s_) << 8) + (F0) + fidx]   \
                                 : 0.f;                                       \
        }                                                                     \
        _Pragma("unroll")                                                     \
        for (int k = 0; k < 4; ++k)                                           \
            r_s[k] = S_prev[((hcS + (F0) + frow + 8 * k) << 6) + sdd];        \
    } while (0)

    LOAD_SLICE(0);

    for (int ft = 0; ft < 8; ++ft) {
        const int f0 = ft * 32;
        __syncthreads();
        phq_t[fidx][srow]      = r_q0;
        phq_t[fidx][srow + 16] = r_q1;
#pragma unroll
        for (int k = 0; k < 8; ++k) phk_t[fidx][srow + 16 * k] = r_k[k];
#pragma unroll
        for (int k = 0; k < 4; ++k) Sst[frow + 8 * k][sdd] = r_s[k];
        __syncthreads();
        if (ft < 7) LOAD_SLICE(f0 + 32);

        if (tid < 256) {
            if (ssActive) {
#pragma unroll 4
                for (int f = 0; f < 32; ++f) {
                    float4 av = *(const float4*)&phq_t[f][tt * 4];
                    float4 bv = *(const float4*)&phk_t[f][ss * 4];
                    acc[0][0] += av.x * bv.x; acc[0][1] += av.x * bv.y;
                    acc[0][2] += av.x * bv.z; acc[0][3] += av.x * bv.w;
                    acc[1][0] += av.y * bv.x; acc[1][1] += av.y * bv.y;
                    acc[1][2] += av.y * bv.z; acc[1][3] += av.y * bv.w;
                    acc[2][0] += av.z * bv.x; acc[2][1] += av.z * bv.y;
                    acc[2][2] += av.z * bv.z; acc[2][3] += av.z * bv.w;
                    acc[3][0] += av.w * bv.x; acc[3][1] += av.w * bv.y;
                    acc[3][2] += av.w * bv.z; acc[3][3] += av.w * bv.w;
                }
            }
        } else {
#pragma unroll 4
            for (int f = 0; f < 32; ++f) {
                float sval = Sst[f][d];
                float4 a0 = *(const float4*)&phq_t[f][tg * 8];
                float4 a1 = *(const float4*)&phq_t[f][tg * 8 + 4];
                acc2[0] += a0.x * sval; acc2[1] += a0.y * sval;
                acc2[2] += a0.z * sval; acc2[3] += a0.w * sval;
                acc2[4] += a1.x * sval; acc2[5] += a1.y * sval;
                acc2[6] += a1.z * sval; acc2[7] += a1.w * sval;
            }
            if (u < 32) {
#pragma unroll
                for (int f = 0; f < 32; ++f)
                    den_acc += phq_t[f][u] * z_lds[f0 + f];
            }
        }
    }
#undef LOAD_SLICE

    if (tid < 256) {
        if (ssActive) {
#pragma unroll
            for (int i = 0; i < 4; ++i) {
                float4 o = make_float4(acc[i][0], acc[i][1], acc[i][2], acc[i][3]);
                *(float4*)&A_lds[(tt * 4 + i) * 132 + ss * 4] = o;
            }
        }
    } else {
#pragma unroll
        for (int i = 0; i < 8; ++i)
            ctx_lds[tg * 8 + i][d] = acc2[i];
        if (u < 32) den_lds[u] = den_acc;
    }
    __syncthreads();

    const int dd = tid & 63;
    const int rg = tid >> 6;
#pragma unroll
    for (int i = 0; i < 4; ++i) {
        int tl = rg * 4 + i;
        int tcr = tb + tl;
        float ctx = ctx_lds[tl][dd];
        float den = den_lds[tl];
        for (int s = 0; s <= tcr; ++s) {
            float a = A_lds[tl * 132 + s];
            ctx += a * v_lds[s * 64 + dd];
            den += a;
        }
        attn[(c * 128 + tcr) * 512 + h * 64 + dd] = ctx / fmaxf(den, 1e-6f);
    }
}

extern "C" void kernel_launch(void* const* d_in, const int* in_sizes, int n_in,
                              void* d_out, int out_size, void* d_ws, size_t ws_size,
                              hipStream_t stream)
{
    const float* x      = (const float*)d_in[0];
    const float* W_qkv  = (const float*)d_in[1];
    const float* b_qkv  = (const float*)d_in[2];
    const float* W_out  = (const float*)d_in[3];
    const float* b_out  = (const float*)d_in[4];
    const float* omega  = (const float*)d_in[5];
    const float* W_poly = (const float*)d_in[6];
    const float* qn     = (const float*)d_in[7];
    const float* qw     = (const float*)d_in[8];
    float* out = (float*)d_out;

    float* ws     = (float*)d_ws;
    float* qkv    = ws;                     // 1024*1536
    float* phi_q  = qkv + 1572864;          // 8*1024*256
    float* phi_k  = phi_q + 2097152;        // 8*1024*256
    float* S_c    = phi_k + 2097152;        // 8*8*256*64
    float* z_c    = S_c + 1048576;          // 8*8*256
    float* S_p    = z_c + 16384;            // 8*8*256*64
    float* z_p    = S_p + 1048576;          // 8*8*256
    float* attn   = z_p + 16384;            // 1024*512
    float* p_qkv  = attn + 524288;          // 2*1024*1536
    float* p_out  = p_qkv + 3145728;        // 4*1024*512

    gemm_part_kernel<<<dim3(24, 16, 2), 256, 0, stream>>>(x, W_qkv, p_qkv, 1024, 1536, 512, 256);
    reduce_bias_kernel<<<1536, 256, 0, stream>>>(p_qkv, b_qkv, qkv, 1572864, 1536, 2);
    features_kernel<<<2048, 256, 0, stream>>>(qkv, omega, W_poly, qn, qw, phi_q, phi_k);
    chunksum_kernel<<<256, 256, 0, stream>>>(phi_k, qkv, S_c, z_c);
    scan_kernel<<<512, 256, 0, stream>>>(S_c, z_c, S_p, z_p);
    attn_kernel<<<dim3(64, 4), 512, 0, stream>>>(phi_q, phi_k, qkv, S_p, z_p, attn);
    gemm_part_kernel<<<dim3(8, 16, 4), 256, 0, stream>>>(attn, W_out, p_out, 1024, 512, 512, 128);
    reduce_bias_kernel<<<512, 256, 0, stream>>>(p_out, b_out, out, 524288, 512, 4);
}